// Round 1
// baseline (453.525 us; speedup 1.0000x reference)
//
#include <hip/hip_runtime.h>
#include <math.h>

// Problem constants (from reference): B=8, S=2048, D=128, fp32.
namespace {
constexpr int Bn = 8;
constexpr int Sn = 2048;
constexpr int Dn = 128;
constexpr int BQ = 64;                 // queries per block
constexpr int BK = 64;                 // keys per iteration
constexpr int QTILES = Sn / BQ;        // 32
constexpr int NKB = Sn / BK;           // 32
constexpr float SCALE = 0.08838834764831845f;  // 1/sqrt(128)
constexpr int QKS = BQ + 4;            // padded LDS stride (68 floats: 16B-aligned, breaks 32-bank stride)
}

// Flash-style attention, fp32, online softmax. One block = 64 query rows of one batch.
// Threads: 256 = 16x16 grid; thread(ty,tx) owns score tile rows 4ty..4ty+3, cols 4tx..4tx+3,
// and output tile rows 4ty..4ty+3, cols 8tx..8tx+7.
__global__ __launch_bounds__(256, 1)
void attn_fwd(const float* __restrict__ qg,
              const float* __restrict__ kg,
              const float* __restrict__ vg,
              const unsigned char* __restrict__ mraw,
              float* __restrict__ outg) {
  __shared__ __align__(16) float Qt[Dn * QKS];   // Q^T: [d][row], 34816 B
  __shared__ __align__(16) float Kt[Dn * QKS];   // K^T: [d][col], 34816 B
  __shared__ __align__(16) float Vs[BK * Dn];    // V:   [j][d],   32768 B
  __shared__ __align__(16) float Pt[BK * BQ];    // P^T: [j][row], 16384 B
  __shared__ float mb[BK];                       // mask bias: 0 or -1e30
  __shared__ int mlayout_s;

  const int tid = threadIdx.x;
  const int b  = blockIdx.x / QTILES;
  const int q0 = (blockIdx.x % QTILES) * BQ;
  const int ty = tid >> 4;   // 0..15
  const int tx = tid & 15;   // 0..15

  // ---- mask storage layout detection: 0=int32, 1=uint8, 2=float32 ----
  // u8 layout: bytes at offset%4!=0 are mask values (~half nonzero).
  // f32 layout: 1.0f = 00 00 80 3f -> bytes %4==2,3 nonzero, %4==1 zero.
  // i32 layout: only byte %4==0 nonzero. First 1024 bytes are safe to read in all layouts.
  {
    unsigned int w = ((const unsigned int*)mraw)[tid];
    int f1  = (w & 0x0000ff00u) ? 1 : 0;
    int f23 = (w & 0xffff0000u) ? 1 : 0;
    int any1  = __syncthreads_or(f1);
    int any23 = __syncthreads_or(f23);
    if (tid == 0) mlayout_s = any1 ? 1 : (any23 ? 2 : 0);
    __syncthreads();
  }
  const int mlayout = mlayout_s;

  const float4* q4 = (const float4*)qg;
  const float4* k4 = (const float4*)kg;
  const float4* v4 = (const float4*)vg;

  // ---- stage Q tile (transposed) ----
  #pragma unroll
  for (int i = 0; i < 8; ++i) {
    int li  = tid + 256 * i;           // 0..2047 float4 slots
    int row = li >> 5;                 // 0..63
    int c4  = li & 31;                 // float4 column
    float4 f = q4[(size_t)(b * Sn + q0 + row) * 32 + c4];
    int d0 = c4 * 4;
    Qt[(d0 + 0) * QKS + row] = f.x;
    Qt[(d0 + 1) * QKS + row] = f.y;
    Qt[(d0 + 2) * QKS + row] = f.z;
    Qt[(d0 + 3) * QKS + row] = f.w;
  }

  float m_i[4], l_i[4], O[4][8];
  #pragma unroll
  for (int r = 0; r < 4; ++r) {
    m_i[r] = -INFINITY;
    l_i[r] = 0.0f;
    #pragma unroll
    for (int c = 0; c < 8; ++c) O[r][c] = 0.0f;
  }

  for (int kb = 0; kb < NKB; ++kb) {
    const int k0 = kb * BK;
    __syncthreads();  // prev PV done reading Vs/Pt (also covers Q staging on iter 0)

    // ---- stage K (transposed) + V (row-major) + mask bias ----
    #pragma unroll
    for (int i = 0; i < 8; ++i) {
      int li  = tid + 256 * i;
      int row = li >> 5;
      int c4  = li & 31;
      float4 f = k4[(size_t)(b * Sn + k0 + row) * 32 + c4];
      int d0 = c4 * 4;
      Kt[(d0 + 0) * QKS + row] = f.x;
      Kt[(d0 + 1) * QKS + row] = f.y;
      Kt[(d0 + 2) * QKS + row] = f.z;
      Kt[(d0 + 3) * QKS + row] = f.w;
      float4 g = v4[(size_t)(b * Sn + k0 + row) * 32 + c4];
      *(float4*)&Vs[row * Dn + d0] = g;
    }
    if (tid < BK) {
      int jj = b * Sn + k0 + tid;
      bool ms;
      if (mlayout == 1)      ms = mraw[jj] != 0;
      else if (mlayout == 2) ms = ((const float*)mraw)[jj] != 0.0f;
      else                   ms = ((const int*)mraw)[jj] != 0;
      mb[tid] = ms ? -1e30f : 0.0f;
    }
    __syncthreads();

    // ---- scores: 4x4 per thread, accumulate over d from LDS ----
    float acc[4][4];
    #pragma unroll
    for (int r = 0; r < 4; ++r)
      #pragma unroll
      for (int c = 0; c < 4; ++c) acc[r][c] = 0.0f;

    const float* qcol = &Qt[4 * ty];
    const float* kcol = &Kt[4 * tx];
    #pragma unroll 4
    for (int d = 0; d < Dn; ++d) {
      float4 qv = *(const float4*)(qcol + d * QKS);
      float4 kv = *(const float4*)(kcol + d * QKS);
      float qa[4] = {qv.x, qv.y, qv.z, qv.w};
      float ka[4] = {kv.x, kv.y, kv.z, kv.w};
      #pragma unroll
      for (int r = 0; r < 4; ++r)
        #pragma unroll
        for (int c = 0; c < 4; ++c)
          acc[r][c] = fmaf(qa[r], ka[c], acc[r][c]);
    }

    float mbv[4];
    #pragma unroll
    for (int c = 0; c < 4; ++c) mbv[c] = mb[4 * tx + c];

    // ---- online softmax update (per row; 16 lanes per row-group share state) ----
    float alpha[4];
    #pragma unroll
    for (int r = 0; r < 4; ++r) {
      float mx = -INFINITY;
      #pragma unroll
      for (int c = 0; c < 4; ++c) {
        float s = fmaf(acc[r][c], SCALE, mbv[c]);  // scale + mask bias (-1e30 if masked)
        acc[r][c] = s;
        mx = fmaxf(mx, s);
      }
      #pragma unroll
      for (int off = 1; off < 16; off <<= 1)
        mx = fmaxf(mx, __shfl_xor(mx, off));
      float mnew = fmaxf(m_i[r], mx);              // finite after first block
      alpha[r] = __expf(m_i[r] - mnew);            // exp(-inf - finite) = 0 on iter 0
      float rs = 0.0f;
      #pragma unroll
      for (int c = 0; c < 4; ++c) {
        float e = __expf(acc[r][c] - mnew);        // masked: exp(~ -1e30) = 0
        acc[r][c] = e;
        rs += e;
      }
      #pragma unroll
      for (int off = 1; off < 16; off <<= 1)
        rs += __shfl_xor(rs, off);
      l_i[r] = l_i[r] * alpha[r] + rs;
      m_i[r] = mnew;
    }

    // ---- write P^T to LDS ----
    #pragma unroll
    for (int c = 0; c < 4; ++c) {
      float4 pc = make_float4(acc[0][c], acc[1][c], acc[2][c], acc[3][c]);
      *(float4*)&Pt[(4 * tx + c) * BQ + 4 * ty] = pc;
    }
    __syncthreads();

    // ---- PV: O[4][8] += P^T[j][rows] * V[j][cols], with rescale ----
    #pragma unroll
    for (int r = 0; r < 4; ++r)
      #pragma unroll
      for (int c = 0; c < 8; ++c) O[r][c] *= alpha[r];

    #pragma unroll 2
    for (int j = 0; j < BK; ++j) {
      float4 p  = *(const float4*)&Pt[j * BQ + 4 * ty];
      float4 va = *(const float4*)&Vs[j * Dn + 8 * tx];
      float4 vb = *(const float4*)&Vs[j * Dn + 8 * tx + 4];
      float pa[4] = {p.x, p.y, p.z, p.w};
      float v8[8] = {va.x, va.y, va.z, va.w, vb.x, vb.y, vb.z, vb.w};
      #pragma unroll
      for (int r = 0; r < 4; ++r)
        #pragma unroll
        for (int c = 0; c < 8; ++c)
          O[r][c] = fmaf(pa[r], v8[c], O[r][c]);
    }
  }

  // ---- epilogue: normalize and store ----
  float4* out4 = (float4*)outg;
  #pragma unroll
  for (int r = 0; r < 4; ++r) {
    float inv = 1.0f / l_i[r];
    float4 a = make_float4(O[r][0] * inv, O[r][1] * inv, O[r][2] * inv, O[r][3] * inv);
    float4 c2 = make_float4(O[r][4] * inv, O[r][5] * inv, O[r][6] * inv, O[r][7] * inv);
    size_t o = (size_t)(b * Sn + q0 + 4 * ty + r) * 32 + 2 * tx;
    out4[o]     = a;
    out4[o + 1] = c2;
  }
}

extern "C" void kernel_launch(void* const* d_in, const int* in_sizes, int n_in,
                              void* d_out, int out_size, void* d_ws, size_t ws_size,
                              hipStream_t stream) {
  const float* q = (const float*)d_in[0];
  const float* k = (const float*)d_in[1];
  const float* v = (const float*)d_in[2];
  const unsigned char* m = (const unsigned char*)d_in[3];
  float* out = (float*)d_out;
  (void)in_sizes; (void)n_in; (void)out_size; (void)d_ws; (void)ws_size;
  attn_fwd<<<dim3(Bn * QTILES), dim3(256), 0, stream>>>(q, k, v, m, out);
}

// Round 2
// 161.126 us; speedup vs baseline: 2.8147x; 2.8147x over previous
//
#include <hip/hip_runtime.h>
#include <math.h>

typedef __attribute__((ext_vector_type(8))) short short8;
typedef __attribute__((ext_vector_type(4))) float floatx4;

namespace {
constexpr int Bn = 8;
constexpr int Sn = 2048;
constexpr int Dn = 128;
constexpr int BQ = 64;                 // queries per block (4 waves x 16 rows)
constexpr int BK = 64;                 // keys per iteration
constexpr int QTILES = Sn / BQ;        // 32
constexpr int NKB = Sn / BK;           // 32
constexpr float SCALE = 0.08838834764831845f;  // 1/sqrt(128)
constexpr int KS = Dn + 8;             // K LDS row stride (ushorts): 272 B, 16B-aligned, bank-uniform
constexpr int PS = BK + 8;             // P LDS row stride (ushorts): 144 B, 16B-aligned
}

__device__ __forceinline__ unsigned short f2bf(float x) {
  union { float f; unsigned u; } a; a.f = x;
  unsigned r = a.u + 0x7fffu + ((a.u >> 16) & 1u);   // RNE to bf16
  return (unsigned short)(r >> 16);
}

// Flash attention, bf16 MFMA 16x16x32. One block = 64 query rows; wave w owns rows 16w..16w+15.
// Score C-layout: row=(lane>>4)*4+reg, col=lane&15 (per tile). A/B frags: [m|n=lane&15][k=(lane>>4)*8+j].
__global__ __launch_bounds__(256, 1)
void attn_fwd(const float* __restrict__ qg, const float* __restrict__ kg,
              const float* __restrict__ vg, const unsigned char* __restrict__ mraw,
              float* __restrict__ outg) {
  __shared__ __align__(16) unsigned short Khi[BK * KS];     // K tile bf16, row-major [key][d], 17408 B
  __shared__ __align__(16) unsigned short Vt[Dn * BK];      // V^T bf16 [d][key], octet-swizzled, 16384 B
  __shared__ __align__(16) unsigned short Pb[4 * 16 * PS];  // per-wave P bf16 [row][key], 9216 B
  __shared__ float mb[BK];                                  // mask bias 0 / -1e30
  __shared__ int mlayout_s;

  const int tid = threadIdx.x;
  const int b  = blockIdx.x & 7;               // batch -> XCD swizzle: one batch per XCD (L2 locality)
  const int q0 = (blockIdx.x >> 3) * BQ;
  const int w  = tid >> 6;
  const int L  = tid & 63;
  const int g  = L >> 4;                       // quad index
  const int c  = L & 15;

  // ---- mask storage layout detection: 0=int32, 1=uint8, 2=float32 ----
  {
    unsigned int wv = ((const unsigned int*)mraw)[tid];
    int f1  = (wv & 0x0000ff00u) ? 1 : 0;
    int f23 = (wv & 0xffff0000u) ? 1 : 0;
    int any1  = __syncthreads_or(f1);
    int any23 = __syncthreads_or(f23);
    if (tid == 0) mlayout_s = any1 ? 1 : (any23 ? 2 : 0);
    __syncthreads();
  }
  const int mlayout = mlayout_s;

  const float4* k4 = (const float4*)kg;
  const float4* v4 = (const float4*)vg;

  // ---- Q fragments in registers, hi/lo split (Q error eliminated from scores) ----
  short8 qh[4], ql[4];
  {
    const float* qrow = qg + (size_t)(b * Sn + q0 + w * 16 + c) * Dn + g * 8;
    #pragma unroll
    for (int kk = 0; kk < 4; ++kk) {
      #pragma unroll
      for (int j = 0; j < 8; ++j) {
        float x = qrow[kk * 32 + j];
        unsigned short h = f2bf(x);
        union { unsigned u; float f; } hv; hv.u = ((unsigned)h) << 16;
        qh[kk][j] = (short)h;
        ql[kk][j] = (short)f2bf(x - hv.f);
      }
    }
  }

  float m_i[4], l_i[4];
  floatx4 O[8];
  #pragma unroll
  for (int r = 0; r < 4; ++r) { m_i[r] = -INFINITY; l_i[r] = 0.0f; }
  #pragma unroll
  for (int n2 = 0; n2 < 8; ++n2) O[n2] = (floatx4){0.f, 0.f, 0.f, 0.f};

  const int krow = tid >> 5;          // 0..7
  const int kc4  = tid & 31;
  const int vjb  = 4 * (tid >> 5);    // key block base 0..28
  const int vdb  = tid & 31;          // dim block /4

  // ---- register prefetch of first K/V tile ----
  float4 kpre[8], vpre[8];
  #pragma unroll
  for (int i = 0; i < 8; ++i)
    kpre[i] = k4[(size_t)(b * Sn + krow + 8 * i) * 32 + kc4];
  #pragma unroll
  for (int it = 0; it < 2; ++it)
    #pragma unroll
    for (int r = 0; r < 4; ++r)
      vpre[it * 4 + r] = v4[(size_t)(b * Sn + vjb + 32 * it + r) * 32 + vdb];

  const unsigned short* kbase = &Khi[c * KS + g * 8];
  const unsigned short* pbase = &Pb[(w * 16 + c) * PS + g * 8];
  unsigned short* pw = &Pb[w * 16 * PS];

  for (int kb = 0; kb < NKB; ++kb) {
    const int k0 = kb * BK;
    __syncthreads();   // prev iteration's Khi/Vt reads complete

    // ---- stage K tile (bf16 row-major) ----
    #pragma unroll
    for (int i = 0; i < 8; ++i) {
      float4 f = kpre[i];
      ushort4 pk = make_ushort4(f2bf(f.x), f2bf(f.y), f2bf(f.z), f2bf(f.w));
      *(ushort4*)&Khi[(krow + 8 * i) * KS + kc4 * 4] = pk;
    }
    // ---- stage V^T (4x4 register transpose, octet XOR swizzle) ----
    #pragma unroll
    for (int it = 0; it < 2; ++it) {
      const int j0 = vjb + 32 * it;
      const int o = j0 >> 3, jlow = j0 & 7;
      float vv[4][4];
      #pragma unroll
      for (int r = 0; r < 4; ++r) {
        float4 f = vpre[it * 4 + r];
        vv[r][0] = f.x; vv[r][1] = f.y; vv[r][2] = f.z; vv[r][3] = f.w;
      }
      #pragma unroll
      for (int t = 0; t < 4; ++t) {
        const int d = 4 * vdb + t;
        const int fsw = (d >> 1) & 7;
        ushort4 pk = make_ushort4(f2bf(vv[0][t]), f2bf(vv[1][t]), f2bf(vv[2][t]), f2bf(vv[3][t]));
        *(ushort4*)&Vt[d * BK + ((o ^ fsw) * 8 + jlow)] = pk;
      }
    }
    if (tid < BK) {
      int jj = b * Sn + k0 + tid;
      bool ms;
      if (mlayout == 1)      ms = mraw[jj] != 0;
      else if (mlayout == 2) ms = ((const float*)mraw)[jj] != 0.0f;
      else                   ms = ((const int*)mraw)[jj] != 0;
      mb[tid] = ms ? -1e30f : 0.0f;
    }
    // ---- prefetch next K/V tile (overlaps with compute below) ----
    if (kb + 1 < NKB) {
      const int kn = k0 + BK;
      #pragma unroll
      for (int i = 0; i < 8; ++i)
        kpre[i] = k4[(size_t)(b * Sn + kn + krow + 8 * i) * 32 + kc4];
      #pragma unroll
      for (int it = 0; it < 2; ++it)
        #pragma unroll
        for (int r = 0; r < 4; ++r)
          vpre[it * 4 + r] = v4[(size_t)(b * Sn + kn + vjb + 32 * it + r) * 32 + vdb];
    }
    __syncthreads();

    // ---- QK^T: 4 key-tiles x 4 ksteps, (qh+ql)*kh ----
    floatx4 acc[4];
    #pragma unroll
    for (int nt = 0; nt < 4; ++nt) acc[nt] = (floatx4){0.f, 0.f, 0.f, 0.f};
    #pragma unroll
    for (int kk = 0; kk < 4; ++kk) {
      #pragma unroll
      for (int nt = 0; nt < 4; ++nt) {
        short8 kf = *(const short8*)(kbase + nt * (16 * KS) + kk * 32);
        acc[nt] = __builtin_amdgcn_mfma_f32_16x16x32_bf16(qh[kk], kf, acc[nt], 0, 0, 0);
        acc[nt] = __builtin_amdgcn_mfma_f32_16x16x32_bf16(ql[kk], kf, acc[nt], 0, 0, 0);
      }
    }

    // ---- online softmax (rows = g*4+r, cols = nt*16+c) ----
    float mbv[4];
    #pragma unroll
    for (int nt = 0; nt < 4; ++nt) mbv[nt] = mb[nt * 16 + c];
    float alpha[4];
    #pragma unroll
    for (int r = 0; r < 4; ++r) {
      float mx = -INFINITY;
      #pragma unroll
      for (int nt = 0; nt < 4; ++nt) {
        float s = fmaf(acc[nt][r], SCALE, mbv[nt]);
        acc[nt][r] = s;
        mx = fmaxf(mx, s);
      }
      #pragma unroll
      for (int off = 1; off < 16; off <<= 1)
        mx = fmaxf(mx, __shfl_xor(mx, off));
      float mnew = fmaxf(m_i[r], mx);
      alpha[r] = __expf(m_i[r] - mnew);
      float rs = 0.0f;
      #pragma unroll
      for (int nt = 0; nt < 4; ++nt) {
        float e = __expf(acc[nt][r] - mnew);
        acc[nt][r] = e;
        rs += e;
      }
      #pragma unroll
      for (int off = 1; off < 16; off <<= 1)
        rs += __shfl_xor(rs, off);
      l_i[r] = l_i[r] * alpha[r] + rs;
      m_i[r] = mnew;
    }

    // ---- P (C-layout) -> LDS bf16 (A-layout source); same-wave region, no barrier needed ----
    #pragma unroll
    for (int nt = 0; nt < 4; ++nt)
      #pragma unroll
      for (int r = 0; r < 4; ++r)
        pw[(g * 4 + r) * PS + nt * 16 + c] = f2bf(acc[nt][r]);

    // ---- rescale O, then PV MFMA ----
    #pragma unroll
    for (int n2 = 0; n2 < 8; ++n2)
      #pragma unroll
      for (int r = 0; r < 4; ++r)
        O[n2][r] *= alpha[r];

    #pragma unroll
    for (int kk = 0; kk < 2; ++kk) {
      short8 pf = *(const short8*)(pbase + kk * 32);
      #pragma unroll
      for (int n2 = 0; n2 < 8; ++n2) {
        const int n = n2 * 16 + c;
        const int o2 = kk * 4 + g;
        const int fsw = (n >> 1) & 7;
        short8 vf = *(const short8*)&Vt[n * BK + ((o2 ^ fsw) * 8)];
        O[n2] = __builtin_amdgcn_mfma_f32_16x16x32_bf16(pf, vf, O[n2], 0, 0, 0);
      }
    }
  }

  // ---- epilogue ----
  float invl[4];
  #pragma unroll
  for (int r = 0; r < 4; ++r) invl[r] = 1.0f / l_i[r];
  float* orow = outg + (size_t)(b * Sn + q0 + w * 16) * Dn;
  #pragma unroll
  for (int n2 = 0; n2 < 8; ++n2)
    #pragma unroll
    for (int r = 0; r < 4; ++r)
      orow[(g * 4 + r) * Dn + n2 * 16 + c] = O[n2][r] * invl[r];
}

extern "C" void kernel_launch(void* const* d_in, const int* in_sizes, int n_in,
                              void* d_out, int out_size, void* d_ws, size_t ws_size,
                              hipStream_t stream) {
  const float* q = (const float*)d_in[0];
  const float* k = (const float*)d_in[1];
  const float* v = (const float*)d_in[2];
  const unsigned char* m = (const unsigned char*)d_in[3];
  float* out = (float*)d_out;
  (void)in_sizes; (void)n_in; (void)out_size; (void)d_ws; (void)ws_size;
  attn_fwd<<<dim3(Bn * QTILES), dim3(256), 0, stream>>>(q, k, v, m, out);
}